// Round 12
// baseline (118.178 us; speedup 1.0000x reference)
//
#include <hip/hip_runtime.h>
#include <stdint.h>

#define LSEQ 1024
#define NB 4
#define KNB 48
#define NFEAT 416   // 16 + 25*16
#define NOUT 128
#define NNODE (NB*LSEQ)

typedef float f32x4 __attribute__((ext_vector_type(4)));
typedef short s16x8 __attribute__((ext_vector_type(8)));

// static device scratch -- fully rewritten every call before use
__device__ float4 g_atoms[NNODE*5];
__device__ float4 g_ca[NNODE];
__device__ ushort g_wbf[NOUT*NFEAT];   // W_edge bf16, row-major [e][f]
__device__ ushort g_wpt[66*16];        // (W_pos.T + b_pos) bf16, [d][c]
__device__ int    g_nbr[NNODE*KNB];
__device__ float  g_dnb[NNODE*KNB];

__constant__ int cPA[24] = {0,2,3,4,1,1,1,1,0,0,0,4,4,3,0,2,3,4,2,3,4,2,3,2};
__constant__ int cPB[24] = {0,2,3,4,0,2,3,4,2,3,4,2,3,2,1,1,1,1,0,0,0,4,4,3};

__device__ __forceinline__ ushort f2bf(float x) {      // RNE (weights)
  unsigned u = __float_as_uint(x);
  u += 0x7fffu + ((u >> 16) & 1u);
  return (ushort)(u >> 16);
}
// pack trunc-bf16(lo), trunc-bf16(hi) into one dword via byte-perm
__device__ __forceinline__ unsigned pack2bf(float lo, float hi) {
  return __builtin_amdgcn_perm(__float_as_uint(hi), __float_as_uint(lo), 0x07060302u);
}

#define DPP_ADD_F(x, CTRL) { int _y = __builtin_amdgcn_mov_dpp(__float_as_int(x), CTRL, 0xF, 0xF, true); x += __int_as_float(_y); }

__device__ __forceinline__ unsigned long long shfl_xor_u64(unsigned long long x, int m) {
  unsigned hi = __shfl_xor((unsigned)(x >> 32), m, 64);
  unsigned lo = __shfl_xor((unsigned)(x & 0xffffffffu), m, 64);
  return ((unsigned long long)hi << 32) | lo;
}

// ---------------- kernel 0: Cb + atom packing (round-1 proven) ----------------
__global__ void k_prep(const float* __restrict__ X) {
  int t = blockIdx.x*256 + threadIdx.x;
  if (t >= NNODE) return;
  const float* p = X + (size_t)t*12;
  float nx=p[0],ny=p[1],nz=p[2];
  float cax=p[3],cay=p[4],caz=p[5];
  float cx=p[6],cy=p[7],cz=p[8];
  float ox=p[9],oy=p[10],oz=p[11];
  float bx=cax-nx, by=cay-ny, bz=caz-nz;
  float ex=cx-cax, ey=cy-cay, ez=cz-caz;
  float ax2 = by*ez - bz*ey;
  float ay2 = bz*ex - bx*ez;
  float az2 = bx*ey - by*ex;
  float cbx = -0.58273431f*ax2 + 0.56802827f*bx - 0.54067466f*ex + cax;
  float cby = -0.58273431f*ay2 + 0.56802827f*by - 0.54067466f*ey + cay;
  float cbz = -0.58273431f*az2 + 0.56802827f*bz - 0.54067466f*ez + caz;
  g_atoms[t*5+0] = make_float4(nx,ny,nz,0.f);
  g_atoms[t*5+1] = make_float4(cax,cay,caz,0.f);
  g_atoms[t*5+2] = make_float4(cx,cy,cz,0.f);
  g_atoms[t*5+3] = make_float4(ox,oy,oz,0.f);
  g_atoms[t*5+4] = make_float4(cbx,cby,cbz,0.f);
  g_ca[t] = make_float4(cax,cay,caz,0.f);
}

// ---------------- kernel 0b: W_edge fp32->bf16 + WposT table ----------------
__global__ void k_wcvt(const float* __restrict__ W, const float* __restrict__ Wpos,
                       const float* __restrict__ bpos) {
  int blk = blockIdx.x, tid = threadIdx.x;
  if (blk < 208) {
    int t = blk*256 + tid;                 // exactly 208*256 = 128*416
    g_wbf[t] = f2bf(W[t]);
  } else {
    for (int t = tid; t < 66*16; t += 256) {
      int d = t >> 4, c = t & 15;
      g_wpt[t] = f2bf(Wpos[c*66 + d] + bpos[c]);
    }
  }
}

// ---------------- kernel 1: exact top-K (round-1 proven: u64 butterfly + owner rescan) ----------------
__global__ __launch_bounds__(256) void k_topk(const float* __restrict__ mask,
                                              float* __restrict__ outIdx) {
  __shared__ float4 sca[LSEQ];
  __shared__ float  sm[LSEQ];
  int b = blockIdx.y;
  for (int t = threadIdx.x; t < LSEQ; t += 256) {
    sca[t] = g_ca[b*LSEQ + t];
    sm[t]  = mask[b*LSEQ + t];
  }
  __syncthreads();
  int wave = threadIdx.x >> 6, lane = threadIdx.x & 63;
  int i = blockIdx.x*4 + wave;
  float4 ci = sca[i];
  float  mi = sm[i];

  float Dv[16];
  float dmax = 0.f;
  #pragma unroll
  for (int q = 0; q < 16; ++q) {
    int j = lane + (q << 6);
    float4 cj = sca[j];
    // bit-exact vs XLA: separate mul/add (no FMA), correctly-rounded sqrt
    float dx = __fsub_rn(cj.x, ci.x);
    float dy = __fsub_rn(cj.y, ci.y);
    float dz = __fsub_rn(cj.z, ci.z);
    float s  = __fadd_rn(__fadd_rn(__fmul_rn(dx,dx), __fmul_rn(dy,dy)), __fmul_rn(dz,dz));
    float sq = __fsqrt_rn(__fadd_rn(s, 1e-6f));
    float d  = __fmul_rn(__fmul_rn(mi, sm[j]), sq);   // mask2 * sqrt(...)
    Dv[q] = d;
    dmax = fmaxf(dmax, d);
  }
  #pragma unroll
  for (int o = 32; o; o >>= 1) dmax = fmaxf(dmax, __shfl_xor(dmax, o, 64));

  unsigned long long key[16];
  unsigned long long lmin = ~0ull;
  #pragma unroll
  for (int q = 0; q < 16; ++q) {
    int j = lane + (q << 6);
    float m2   = __fmul_rn(mi, sm[j]);
    float dadj = __fadd_rn(Dv[q], __fmul_rn(__fsub_rn(1.0f, m2), dmax));
    key[q] = ((unsigned long long)__float_as_uint(dadj) << 32) | (unsigned)j;
    lmin = (key[q] < lmin) ? key[q] : lmin;
  }

  size_t row = (size_t)(b*LSEQ + i);
  for (int k = 0; k < KNB; ++k) {
    unsigned long long m = lmin;
    #pragma unroll
    for (int o = 1; o < 64; o <<= 1) {
      unsigned long long other = shfl_xor_u64(m, o);
      m = (other < m) ? other : m;
    }
    if (lane == 0) {
      unsigned j = (unsigned)(m & 0xffffffffu);
      g_nbr[row*KNB + k] = (int)j;
      g_dnb[row*KNB + k] = __uint_as_float((unsigned)(m >> 32));
      outIdx[row*KNB + k] = (float)(int)j;
    }
    if (m == lmin) {                 // unique owner (index in low bits)
      unsigned long long nm = ~0ull;
      #pragma unroll
      for (int q = 0; q < 16; ++q) {
        if (key[q] == m) key[q] = ~0ull;
        nm = (key[q] < nm) ? key[q] : nm;
      }
      lmin = nm;
    }
  }
}

// ---------------- kernel 2: features (chain-RBF, swizzled LDS) + pipelined MFMA + fused LN ----------------
__global__ __launch_bounds__(256, 4) void k_edge(
    const int* __restrict__ ridx, const int* __restrict__ chain,
    const float* __restrict__ lng, const float* __restrict__ lnb,
    float* __restrict__ out)
{
  __shared__ __align__(16) ushort featb[KNB*256];   // 24,576 B; 32B slots, slot^(k&7) swizzle
  __shared__ float4 atN[KNB*5];
  __shared__ float4 atI[5];
  __shared__ float  sdn[KNB];
  __shared__ int    sdd[KNB];
  __shared__ float2 sstat[KNB][4];
  __shared__ float2 rstat[KNB];

  int node = blockIdx.x;               // b*LSEQ + i
  int b = node >> 10;
  size_t ebase = (size_t)node * KNB;
  int t = threadIdx.x;

  // ---- phase A: scalars + atom gather
  if (t < KNB) {
    int j = g_nbr[ebase + t];
    sdn[t] = g_dnb[ebase + t];
    int off = ridx[node] - ridx[b*LSEQ + j];
    bool same = (chain[node] == chain[b*LSEQ + j]);
    int dcl = min(max(off + 32, 0), 64);
    sdd[t] = same ? dcl : 65;
  }
  if (t >= 64 && t < 69) atI[t-64] = g_atoms[node*5 + (t-64)];
  for (int u = t; u < KNB*5; u += 256) {
    int k = u / 5, a = u % 5;
    atN[u] = g_atoms[(b*LSEQ + g_nbr[ebase + k])*5 + a];
  }
  __syncthreads();

  // ---- chain-RBF writer: centers equispaced by DLT in u-units, so the
  //      Gaussian ratio e[m+1]/e[m] is geometric (x INVK per step).
  //      Two 8-element chains from both ends avoid underflow at the peak.
  //      u0 = 0.96089793*d - 1.92179585 ; e[m] = exp2(-(u0 - m*DLT)^2)
  auto rbf_store = [&](int k, int slot, float d) {
    const float TDLT = 2.56239448f;     // 2*DLT
    const float NDSQ = -1.64146638f;    // -DLT^2
    const float INVK = 0.10274013f;     // exp2(-2*DLT^2)
    float u0  = __fmaf_rn(d, 0.96089793f, -1.92179585f);
    float u15 = u0 - 19.21795854f;      // u at center 15
    float e[16];
    float eA = __builtin_amdgcn_exp2f(-(u0*u0));
    float rA = __builtin_amdgcn_exp2f(__fmaf_rn(u0, TDLT, NDSQ));
    float eB = __builtin_amdgcn_exp2f(-(u15*u15));
    float rB = __builtin_amdgcn_exp2f(__fmaf_rn(u15, -TDLT, NDSQ));
    e[0] = eA; e[15] = eB;
    #pragma unroll
    for (int j2 = 1; j2 < 8; ++j2) {
      eA *= rA; rA *= INVK; e[j2] = eA;        // ascending from m=0
      eB *= rB; rB *= INVK; e[15-j2] = eB;     // descending from m=15
    }
    union { s16x8 v; unsigned w[4]; } a0, a1;
    #pragma unroll
    for (int q = 0; q < 4; ++q) {
      a0.w[q] = pack2bf(e[2*q],   e[2*q+1]);
      a1.w[q] = pack2bf(e[8+2*q], e[8+2*q+1]);
    }
    ushort* fp = &featb[k*256 + ((slot ^ (k & 7)) << 4)];
    *(s16x8*)fp       = a0.v;
    *(s16x8*)(fp + 8) = a1.v;
  };

  // ---- feat pass 0: E_pos (slot 0) + RBF p=0..12 (slots 1..13)
  if (t < 96) {
    int k = t >> 1, h = t & 1;
    *(s16x8*)&featb[k*256 + ((0 ^ (k & 7)) << 4) + h*8] =
        *(const s16x8*)&g_wpt[sdd[k]*16 + h*8];
  }
  for (int u = t; u < KNB*13; u += 256) {
    int k = u / 13, p = u % 13;
    float d;
    if (p == 0) d = sdn[k];
    else {
      float4 A = atI[cPA[p-1]];
      float4 Bv = atN[k*5 + cPB[p-1]];
      float dx = A.x-Bv.x, dy = A.y-Bv.y, dz = A.z-Bv.z;
      d = sqrtf(dx*dx + dy*dy + dz*dz + 1e-6f);
    }
    rbf_store(k, p + 1, d);
  }
  __syncthreads();

  int ln = t & 63, wv = t >> 6;
  int fr = ln & 15, fq = ln >> 4;
  int n0 = wv * 32;
  f32x4 acc[3][2];
  #pragma unroll
  for (int mt = 0; mt < 3; ++mt) { acc[mt][0] = (f32x4)0.f; acc[mt][1] = (f32x4)0.f; }
  const ushort* w0 = &g_wbf[(n0 + fr)*NFEAT];
  const ushort* w1 = &g_wbf[(n0 + 16 + fr)*NFEAT];

  // 2-stage-pipelined GEMM pass: featb local k from 0, W offset WOFF
#define GEMM_PASS(WOFF, NSTEPS)                                                     \
  {                                                                                 \
    s16x8 cw0 = *(const s16x8*)&w0[(WOFF) + fq*8];                                  \
    s16x8 cw1 = *(const s16x8*)&w1[(WOFF) + fq*8];                                  \
    _Pragma("unroll")                                                               \
    for (int s = 0; s < (NSTEPS); ++s) {                                            \
      int kk = s*32 + fq*8;                                                         \
      s16x8 nw0, nw1;                                                               \
      if (s + 1 < (NSTEPS)) {                                                       \
        nw0 = *(const s16x8*)&w0[(WOFF) + kk + 32];                                 \
        nw1 = *(const s16x8*)&w1[(WOFF) + kk + 32];                                 \
      }                                                                             \
      _Pragma("unroll")                                                             \
      for (int mt = 0; mt < 3; ++mt) {                                              \
        int row = mt*16 + fr;                                                       \
        s16x8 af = *(const s16x8*)&featb[row*256 + (((kk >> 4) ^ (fr & 7)) << 4) + (kk & 8)]; \
        acc[mt][0] = __builtin_amdgcn_mfma_f32_16x16x32_bf16(af, cw0, acc[mt][0], 0, 0, 0);   \
        acc[mt][1] = __builtin_amdgcn_mfma_f32_16x16x32_bf16(af, cw1, acc[mt][1], 0, 0, 0);   \
      }                                                                             \
      if (s + 1 < (NSTEPS)) { cw0 = nw0; cw1 = nw1; }                               \
    }                                                                               \
  }

  // ---- GEMM pass 0: features [0,224), 7 K-steps
  GEMM_PASS(0, 7)
  __syncthreads();   // pass-0 reads done before overwrite

  // ---- feat pass 1: RBF p=13..24 (slots 0..11)
  for (int u = t; u < KNB*12; u += 256) {
    int k = u / 12, p = 13 + u % 12;
    float4 A = atI[cPA[p-1]];
    float4 Bv = atN[k*5 + cPB[p-1]];
    float dx = A.x-Bv.x, dy = A.y-Bv.y, dz = A.z-Bv.z;
    rbf_store(k, p - 13, sqrtf(dx*dx + dy*dy + dz*dz + 1e-6f));
  }
  __syncthreads();

  // ---- GEMM pass 1: features [224,416), 6 K-steps
  GEMM_PASS(224, 6)

  // ---- fused LayerNorm epilogue; row sums via DPP row_ror (VALU-only)
  #pragma unroll
  for (int mt = 0; mt < 3; ++mt)
    #pragma unroll
    for (int i2 = 0; i2 < 4; ++i2) {
      float v0 = acc[mt][0][i2], v1 = acc[mt][1][i2];
      float s = v0 + v1, sq = v0*v0 + v1*v1;
      DPP_ADD_F(s, 0x128) DPP_ADD_F(s, 0x124) DPP_ADD_F(s, 0x122) DPP_ADD_F(s, 0x121)
      DPP_ADD_F(sq, 0x128) DPP_ADD_F(sq, 0x124) DPP_ADD_F(sq, 0x122) DPP_ADD_F(sq, 0x121)
      if (fr == 0) sstat[mt*16 + fq*4 + i2][wv] = make_float2(s, sq);
    }
  __syncthreads();
  if (t < KNB) {
    float s = 0.f, sq = 0.f;
    #pragma unroll
    for (int w = 0; w < 4; ++w) { float2 pp = sstat[t][w]; s += pp.x; sq += pp.y; }
    float mu  = s * (1.0f/128.0f);
    float var = sq * (1.0f/128.0f) - mu*mu;
    rstat[t] = make_float2(mu, rsqrtf(var + 1e-5f));
  }
  __syncthreads();
  float gn0 = lng[n0+fr], gn1 = lng[n0+16+fr];
  float bn0 = lnb[n0+fr], bn1 = lnb[n0+16+fr];
  #pragma unroll
  for (int mt = 0; mt < 3; ++mt)
    #pragma unroll
    for (int i2 = 0; i2 < 4; ++i2) {
      int row = mt*16 + fq*4 + i2;
      float2 mr = rstat[row];
      size_t ob = (ebase + row) * NOUT;
      out[ob + n0 + fr]      = (acc[mt][0][i2] - mr.x) * mr.y * gn0 + bn0;
      out[ob + n0 + 16 + fr] = (acc[mt][1][i2] - mr.x) * mr.y * gn1 + bn1;
    }
}

extern "C" void kernel_launch(void* const* d_in, const int* in_sizes, int n_in,
                              void* d_out, int out_size, void* d_ws, size_t ws_size,
                              hipStream_t stream) {
  const float* X     = (const float*)d_in[0];
  const float* mask  = (const float*)d_in[1];
  const int*   ridx  = (const int*)d_in[2];
  const int*   chain = (const int*)d_in[3];
  const float* Wpos  = (const float*)d_in[4];
  const float* bpos  = (const float*)d_in[5];
  const float* Wedge = (const float*)d_in[6];
  const float* lng   = (const float*)d_in[7];
  const float* lnb   = (const float*)d_in[8];
  float* out = (float*)d_out;
  float* outIdx = out + (size_t)NNODE*KNB*NOUT;

  k_prep<<<dim3(NNODE/256), dim3(256), 0, stream>>>(X);
  k_wcvt<<<dim3(209), dim3(256), 0, stream>>>(Wedge, Wpos, bpos);
  k_topk<<<dim3(LSEQ/4, NB), dim3(256), 0, stream>>>(mask, outIdx);
  k_edge<<<dim3(NNODE), dim3(256), 0, stream>>>(ridx, chain, lng, lnb, out);
}

// Round 13
// 102.922 us; speedup vs baseline: 1.1482x; 1.1482x over previous
//
#include <hip/hip_runtime.h>
#include <stdint.h>

#define LSEQ 1024
#define NB 4
#define KNB 48
#define NFEAT 416   // 16 + 25*16
#define NOUT 128
#define NNODE (NB*LSEQ)

typedef float f32x4 __attribute__((ext_vector_type(4)));
typedef short s16x8 __attribute__((ext_vector_type(8)));

// static device scratch -- fully rewritten every call before use
__device__ float4 g_atoms[NNODE*5];
__device__ float4 g_ca[NNODE];
__device__ ushort g_wbf[NOUT*NFEAT];   // W_edge bf16, row-major [e][f]
__device__ ushort g_wpt[66*16];        // (W_pos.T + b_pos) bf16, [d][c]

__constant__ int cPA[24] = {0,2,3,4,1,1,1,1,0,0,0,4,4,3,0,2,3,4,2,3,4,2,3,2};
__constant__ int cPB[24] = {0,2,3,4,0,2,3,4,2,3,4,2,3,2,1,1,1,1,0,0,0,4,4,3};

__device__ __forceinline__ ushort f2bf(float x) {      // RNE (weights)
  unsigned u = __float_as_uint(x);
  u += 0x7fffu + ((u >> 16) & 1u);
  return (ushort)(u >> 16);
}
// pack trunc-bf16(lo), trunc-bf16(hi) into one dword via byte-perm
__device__ __forceinline__ unsigned pack2bf(float lo, float hi) {
  return __builtin_amdgcn_perm(__float_as_uint(hi), __float_as_uint(lo), 0x07060302u);
}

#define DPP_ADD_F(x, CTRL) { int _y = __builtin_amdgcn_mov_dpp(__float_as_int(x), CTRL, 0xF, 0xF, true); x += __int_as_float(_y); }
#define DPP_MIN_U(x, CTRL) { unsigned _y = (unsigned)__builtin_amdgcn_mov_dpp((int)(x), CTRL, 0xF, 0xF, true); x = min(x, _y); }

__device__ __forceinline__ unsigned wave_umin(unsigned x) {
  DPP_MIN_U(x, 0x128) DPP_MIN_U(x, 0x124) DPP_MIN_U(x, 0x122) DPP_MIN_U(x, 0x121)
  x = min(x, (unsigned)__shfl_xor((int)x, 16, 64));
  x = min(x, (unsigned)__shfl_xor((int)x, 32, 64));
  return x;
}

// ---------------- kernel 0: atoms/Cb + W->bf16 + WposT table, one dispatch ----------------
__global__ void k_pre(const float* __restrict__ X, const float* __restrict__ W,
                      const float* __restrict__ Wpos, const float* __restrict__ bpos) {
  int blk = blockIdx.x, tid = threadIdx.x;
  if (blk < 16) {
    int t = blk*256 + tid;
    const float* p = X + (size_t)t*12;
    float nx=p[0],ny=p[1],nz=p[2];
    float cax=p[3],cay=p[4],caz=p[5];
    float cx=p[6],cy=p[7],cz=p[8];
    float ox=p[9],oy=p[10],oz=p[11];
    float bx=cax-nx, by=cay-ny, bz=caz-nz;
    float ex=cx-cax, ey=cy-cay, ez=cz-caz;
    float ax2 = by*ez - bz*ey;
    float ay2 = bz*ex - bx*ez;
    float az2 = bx*ey - by*ex;
    float cbx = -0.58273431f*ax2 + 0.56802827f*bx - 0.54067466f*ex + cax;
    float cby = -0.58273431f*ay2 + 0.56802827f*by - 0.54067466f*ey + cay;
    float cbz = -0.58273431f*az2 + 0.56802827f*bz - 0.54067466f*ez + caz;
    g_atoms[t*5+0] = make_float4(nx,ny,nz,0.f);
    g_atoms[t*5+1] = make_float4(cax,cay,caz,0.f);
    g_atoms[t*5+2] = make_float4(cx,cy,cz,0.f);
    g_atoms[t*5+3] = make_float4(ox,oy,oz,0.f);
    g_atoms[t*5+4] = make_float4(cbx,cby,cbz,0.f);
    g_ca[t] = make_float4(cax,cay,caz,0.f);
  } else if (blk < 224) {
    int t = (blk-16)*256 + tid;            // exactly 208*256 = 128*416
    g_wbf[t] = f2bf(W[t]);
  } else {
    for (int t = tid; t < 66*16; t += 256) {
      int d = t >> 4, c = t & 15;
      g_wpt[t] = f2bf(Wpos[c*66 + d] + bpos[c]);
    }
  }
}

// ---------------- kernel 1: FUSED per-node top-K + features + MFMA + LN ----------------
__global__ __launch_bounds__(256, 4) void k_edge(
    const float* __restrict__ mask,
    const int* __restrict__ ridx, const int* __restrict__ chain,
    const float* __restrict__ lng, const float* __restrict__ lnb,
    float* __restrict__ out, float* __restrict__ outIdx)
{
  // 24,576 B region, time-multiplexed:
  //   phase T (top-k): sca[1024] float4 (16 KB) + qhi[16][64], qlo[16][64] (8 KB)
  //   phase F (feat/GEMM): featb[48*256] bf16 (24,576 B; 32B slots, slot^(k&7) swizzle)
  __shared__ __align__(16) unsigned char smem[KNB*256*2];
  ushort*   featb = (ushort*)smem;
  float4*   sca   = (float4*)smem;                       // [1024]
  unsigned* qhi   = (unsigned*)(smem + 16384);           // [pos][lane], pos-major
  unsigned* qlo   = (unsigned*)(smem + 16384 + 4096);
  __shared__ float4 atN[KNB*5];
  __shared__ float4 atI[5];
  __shared__ float  sdn[KNB];
  __shared__ int    snbr[KNB];
  __shared__ int    sdd[KNB];
  __shared__ float2 sstat[KNB][4];
  __shared__ float2 rstat[KNB];

  int node = blockIdx.x;               // b*LSEQ + irow
  int b = node >> 10;
  int irow = node & 1023;
  size_t ebase = (size_t)node * KNB;
  int t = threadIdx.x;
  int ln = t & 63, wv = t >> 6;

  // ---- phase 0: stage Ca+mask (all threads) + atI (wave 1)
  for (int u = t; u < LSEQ; u += 256) {
    float4 c = g_ca[b*LSEQ + u];
    c.w = mask[b*LSEQ + u];
    sca[u] = c;
  }
  if (t >= 64 && t < 69) atI[t-64] = g_atoms[node*5 + (t-64)];
  __syncthreads();

  // ---- phase T: wave 0 computes this node's exact top-48 (bit-exact keys)
  if (wv == 0) {
    float4 ci = sca[irow];
    float  mi = ci.w;
    float Dv[16]; float dmax = 0.f;
    #pragma unroll
    for (int q = 0; q < 16; ++q) {
      int j = ln + (q << 6);
      float4 cj = sca[j];
      // bit-exact vs XLA: separate mul/add (no FMA), correctly-rounded sqrt
      float dx = __fsub_rn(cj.x, ci.x);
      float dy = __fsub_rn(cj.y, ci.y);
      float dz = __fsub_rn(cj.z, ci.z);
      float s  = __fadd_rn(__fadd_rn(__fmul_rn(dx,dx), __fmul_rn(dy,dy)), __fmul_rn(dz,dz));
      float sq = __fsqrt_rn(__fadd_rn(s, 1e-6f));
      float d  = __fmul_rn(__fmul_rn(mi, cj.w), sq);
      Dv[q] = d;
      dmax = fmaxf(dmax, d);
    }
    #pragma unroll
    for (int o = 32; o; o >>= 1) dmax = fmaxf(dmax, __shfl_xor(dmax, o, 64));

    unsigned long long key[16];
    #pragma unroll
    for (int q = 0; q < 16; ++q) {
      int j = ln + (q << 6);
      float m2   = __fmul_rn(mi, sca[j].w);
      float dadj = __fadd_rn(Dv[q], __fmul_rn(__fsub_rn(1.0f, m2), dmax));
      key[q] = ((unsigned long long)__float_as_uint(dadj) << 32) | (unsigned)j;
    }

    // Batcher odd-even mergesort of the 16 per-lane keys (ascending)
    #pragma unroll
    for (int p = 1; p < 16; p <<= 1)
      #pragma unroll
      for (int k = p; k >= 1; k >>= 1)
        #pragma unroll
        for (int j = k & (p - 1); j + k < 16; j += 2*k)
          #pragma unroll
          for (int u = 0; u < k; ++u)
            if (u + j + k < 16 && ((u + j) / (2*p) == (u + j + k) / (2*p))) {
              unsigned long long a = key[u+j], c2 = key[u+j+k];
              if (a > c2) { key[u+j] = c2; key[u+j+k] = a; }
            }

    #pragma unroll
    for (int q = 0; q < 16; ++q) {
      qhi[q*64 + ln] = (unsigned)(key[q] >> 32);
      qlo[q*64 + ln] = (unsigned)key[q];
    }
    // no wave-internal barrier needed: each lane re-reads only its own queue

    unsigned hhi = (unsigned)(key[0] >> 32), hlo = (unsigned)key[0];
    int pos = 0;
    for (int k = 0; k < KNB; ++k) {
      unsigned mh = wave_umin(hhi);
      unsigned long long bmask = __ballot(hhi == mh);
      bool own;
      if (__popcll(bmask) == 1) {
        own = (hhi == mh);
      } else {                            // hi tie: min index wins
        unsigned jv = (hhi == mh) ? hlo : 0xFFFFFFFFu;
        unsigned mj = wave_umin(jv);
        own = (hhi == mh) && (hlo == mj);
      }
      if (own) {
        snbr[k] = (int)hlo;
        sdn[k]  = __uint_as_float(mh);
        outIdx[ebase + k] = (float)(int)hlo;
        ++pos;
        if (pos < 16) { hhi = qhi[pos*64 + ln]; hlo = qlo[pos*64 + ln]; }
        else          { hhi = 0xFFFFFFFFu; hlo = 0xFFFFFFFFu; }
      }
    }
  }
  __syncthreads();   // sca+queues dead; snbr/sdn valid; featb region free

  // ---- phase A: scalars + atom gather
  if (t < KNB) {
    int j = snbr[t];
    int off = ridx[node] - ridx[b*LSEQ + j];
    bool same = (chain[node] == chain[b*LSEQ + j]);
    int dcl = min(max(off + 32, 0), 64);
    sdd[t] = same ? dcl : 65;
  }
  for (int u = t; u < KNB*5; u += 256) {
    int k = u / 5, a = u % 5;
    atN[u] = g_atoms[(b*LSEQ + snbr[k])*5 + a];
  }
  __syncthreads();

  // ---- chain-RBF writer: centers equispaced by DLT in u-units, so the
  //      Gaussian ratio e[m+1]/e[m] is geometric (x INVK per step).
  //      Two 8-element chains from both ends avoid underflow at the peak.
  auto rbf_store = [&](int k, int slot, float d) {
    const float TDLT = 2.56239448f;     // 2*DLT
    const float NDSQ = -1.64146638f;    // -DLT^2
    const float INVK = 0.10274013f;     // exp2(-2*DLT^2)
    float u0  = __fmaf_rn(d, 0.96089793f, -1.92179585f);
    float u15 = u0 - 19.21795854f;      // u at center 15
    float e[16];
    float eA = __builtin_amdgcn_exp2f(-(u0*u0));
    float rA = __builtin_amdgcn_exp2f(__fmaf_rn(u0, TDLT, NDSQ));
    float eB = __builtin_amdgcn_exp2f(-(u15*u15));
    float rB = __builtin_amdgcn_exp2f(__fmaf_rn(u15, -TDLT, NDSQ));
    e[0] = eA; e[15] = eB;
    #pragma unroll
    for (int j2 = 1; j2 < 8; ++j2) {
      eA *= rA; rA *= INVK; e[j2] = eA;        // ascending from m=0
      eB *= rB; rB *= INVK; e[15-j2] = eB;     // descending from m=15
    }
    union { s16x8 v; unsigned w[4]; } a0, a1;
    #pragma unroll
    for (int q = 0; q < 4; ++q) {
      a0.w[q] = pack2bf(e[2*q],   e[2*q+1]);
      a1.w[q] = pack2bf(e[8+2*q], e[8+2*q+1]);
    }
    ushort* fp = &featb[k*256 + ((slot ^ (k & 7)) << 4)];
    *(s16x8*)fp       = a0.v;
    *(s16x8*)(fp + 8) = a1.v;
  };

  // ---- feat pass 0: E_pos (slot 0) + RBF p=0..12 (slots 1..13)
  if (t < 96) {
    int k = t >> 1, h = t & 1;
    *(s16x8*)&featb[k*256 + ((0 ^ (k & 7)) << 4) + h*8] =
        *(const s16x8*)&g_wpt[sdd[k]*16 + h*8];
  }
  for (int u = t; u < KNB*13; u += 256) {
    int k = u / 13, p = u % 13;
    float d;
    if (p == 0) d = sdn[k];
    else {
      float4 A = atI[cPA[p-1]];
      float4 Bv = atN[k*5 + cPB[p-1]];
      float dx = A.x-Bv.x, dy = A.y-Bv.y, dz = A.z-Bv.z;
      d = sqrtf(dx*dx + dy*dy + dz*dz + 1e-6f);
    }
    rbf_store(k, p + 1, d);
  }
  __syncthreads();

  int fr = ln & 15, fq = ln >> 4;
  int n0 = wv * 32;
  f32x4 acc[3][2];
  #pragma unroll
  for (int mt = 0; mt < 3; ++mt) { acc[mt][0] = (f32x4)0.f; acc[mt][1] = (f32x4)0.f; }
  const ushort* w0 = &g_wbf[(n0 + fr)*NFEAT];
  const ushort* w1 = &g_wbf[(n0 + 16 + fr)*NFEAT];

  // 2-stage-pipelined GEMM pass: featb local k from 0, W offset WOFF
#define GEMM_PASS(WOFF, NSTEPS)                                                     \
  {                                                                                 \
    s16x8 cw0 = *(const s16x8*)&w0[(WOFF) + fq*8];                                  \
    s16x8 cw1 = *(const s16x8*)&w1[(WOFF) + fq*8];                                  \
    _Pragma("unroll")                                                               \
    for (int s = 0; s < (NSTEPS); ++s) {                                            \
      int kk = s*32 + fq*8;                                                         \
      s16x8 nw0, nw1;                                                               \
      if (s + 1 < (NSTEPS)) {                                                       \
        nw0 = *(const s16x8*)&w0[(WOFF) + kk + 32];                                 \
        nw1 = *(const s16x8*)&w1[(WOFF) + kk + 32];                                 \
      }                                                                             \
      _Pragma("unroll")                                                             \
      for (int mt = 0; mt < 3; ++mt) {                                              \
        int row = mt*16 + fr;                                                       \
        s16x8 af = *(const s16x8*)&featb[row*256 + (((kk >> 4) ^ (fr & 7)) << 4) + (kk & 8)]; \
        acc[mt][0] = __builtin_amdgcn_mfma_f32_16x16x32_bf16(af, cw0, acc[mt][0], 0, 0, 0);   \
        acc[mt][1] = __builtin_amdgcn_mfma_f32_16x16x32_bf16(af, cw1, acc[mt][1], 0, 0, 0);   \
      }                                                                             \
      if (s + 1 < (NSTEPS)) { cw0 = nw0; cw1 = nw1; }                               \
    }                                                                               \
  }

  // ---- GEMM pass 0: features [0,224), 7 K-steps
  GEMM_PASS(0, 7)
  __syncthreads();   // pass-0 reads done before overwrite

  // ---- feat pass 1: RBF p=13..24 (slots 0..11)
  for (int u = t; u < KNB*12; u += 256) {
    int k = u / 12, p = 13 + u % 12;
    float4 A = atI[cPA[p-1]];
    float4 Bv = atN[k*5 + cPB[p-1]];
    float dx = A.x-Bv.x, dy = A.y-Bv.y, dz = A.z-Bv.z;
    rbf_store(k, p - 13, sqrtf(dx*dx + dy*dy + dz*dz + 1e-6f));
  }
  __syncthreads();

  // ---- GEMM pass 1: features [224,416), 6 K-steps
  GEMM_PASS(224, 6)

  // ---- fused LayerNorm epilogue; row sums via DPP row_ror (VALU-only)
  #pragma unroll
  for (int mt = 0; mt < 3; ++mt)
    #pragma unroll
    for (int i2 = 0; i2 < 4; ++i2) {
      float v0 = acc[mt][0][i2], v1 = acc[mt][1][i2];
      float s = v0 + v1, sq = v0*v0 + v1*v1;
      DPP_ADD_F(s, 0x128) DPP_ADD_F(s, 0x124) DPP_ADD_F(s, 0x122) DPP_ADD_F(s, 0x121)
      DPP_ADD_F(sq, 0x128) DPP_ADD_F(sq, 0x124) DPP_ADD_F(sq, 0x122) DPP_ADD_F(sq, 0x121)
      if (fr == 0) sstat[mt*16 + fq*4 + i2][wv] = make_float2(s, sq);
    }
  __syncthreads();
  if (t < KNB) {
    float s = 0.f, sq = 0.f;
    #pragma unroll
    for (int w = 0; w < 4; ++w) { float2 pp = sstat[t][w]; s += pp.x; sq += pp.y; }
    float mu  = s * (1.0f/128.0f);
    float var = sq * (1.0f/128.0f) - mu*mu;
    rstat[t] = make_float2(mu, rsqrtf(var + 1e-5f));
  }
  __syncthreads();
  float gn0 = lng[n0+fr], gn1 = lng[n0+16+fr];
  float bn0 = lnb[n0+fr], bn1 = lnb[n0+16+fr];
  #pragma unroll
  for (int mt = 0; mt < 3; ++mt)
    #pragma unroll
    for (int i2 = 0; i2 < 4; ++i2) {
      int row = mt*16 + fq*4 + i2;
      float2 mr = rstat[row];
      size_t ob = (ebase + row) * NOUT;
      out[ob + n0 + fr]      = (acc[mt][0][i2] - mr.x) * mr.y * gn0 + bn0;
      out[ob + n0 + 16 + fr] = (acc[mt][1][i2] - mr.x) * mr.y * gn1 + bn1;
    }
}

extern "C" void kernel_launch(void* const* d_in, const int* in_sizes, int n_in,
                              void* d_out, int out_size, void* d_ws, size_t ws_size,
                              hipStream_t stream) {
  const float* X     = (const float*)d_in[0];
  const float* mask  = (const float*)d_in[1];
  const int*   ridx  = (const int*)d_in[2];
  const int*   chain = (const int*)d_in[3];
  const float* Wpos  = (const float*)d_in[4];
  const float* bpos  = (const float*)d_in[5];
  const float* Wedge = (const float*)d_in[6];
  const float* lng   = (const float*)d_in[7];
  const float* lnb   = (const float*)d_in[8];
  float* out = (float*)d_out;
  float* outIdx = out + (size_t)NNODE*KNB*NOUT;

  k_pre<<<dim3(225), dim3(256), 0, stream>>>(X, Wedge, Wpos, bpos);
  k_edge<<<dim3(NNODE), dim3(256), 0, stream>>>(mask, ridx, chain, lng, lnb, out, outIdx);
}

// Round 14
// 81.141 us; speedup vs baseline: 1.4565x; 1.2684x over previous
//
#include <hip/hip_runtime.h>
#include <stdint.h>

#define LSEQ 1024
#define NB 4
#define KNB 48
#define NFEAT 416   // 16 + 25*16
#define NOUT 128
#define NNODE (NB*LSEQ)

typedef float f32x4 __attribute__((ext_vector_type(4)));
typedef short s16x8 __attribute__((ext_vector_type(8)));

// static device scratch -- fully rewritten every call before use
__device__ float4 g_atoms[NNODE*5];
__device__ ushort g_wbf[NOUT*NFEAT];   // W_edge bf16, row-major [e][f]
__device__ ushort g_wpt[66*16];        // (W_pos.T + b_pos) bf16, [d][c]
__device__ int    g_nbr[NNODE*KNB];
__device__ float  g_dnb[NNODE*KNB];

__constant__ int cPA[24] = {0,2,3,4,1,1,1,1,0,0,0,4,4,3,0,2,3,4,2,3,4,2,3,2};
__constant__ int cPB[24] = {0,2,3,4,0,2,3,4,2,3,4,2,3,2,1,1,1,1,0,0,0,4,4,3};

__device__ __forceinline__ ushort f2bf(float x) {      // RNE (weights)
  unsigned u = __float_as_uint(x);
  u += 0x7fffu + ((u >> 16) & 1u);
  return (ushort)(u >> 16);
}
// pack trunc-bf16(lo), trunc-bf16(hi) into one dword via byte-perm
__device__ __forceinline__ unsigned pack2bf(float lo, float hi) {
  return __builtin_amdgcn_perm(__float_as_uint(hi), __float_as_uint(lo), 0x07060302u);
}

#define DPP_ADD_F(x, CTRL) { int _y = __builtin_amdgcn_mov_dpp(__float_as_int(x), CTRL, 0xF, 0xF, true); x += __int_as_float(_y); }
#define DPP_MIN_U(x, CTRL) { unsigned _y = (unsigned)__builtin_amdgcn_mov_dpp((int)(x), CTRL, 0xF, 0xF, true); x = min(x, _y); }

__device__ __forceinline__ unsigned wave_umin(unsigned x) {
  DPP_MIN_U(x, 0x128) DPP_MIN_U(x, 0x124) DPP_MIN_U(x, 0x122) DPP_MIN_U(x, 0x121)
  x = min(x, (unsigned)__shfl_xor((int)x, 16, 64));
  x = min(x, (unsigned)__shfl_xor((int)x, 32, 64));
  return x;
}

// ---------------- kernel 1: prep blocks + exact top-K blocks, one dispatch (r11 proven) ----------------
__global__ __launch_bounds__(256) void k_front(
    const float* __restrict__ X, const float* __restrict__ mask,
    const float* __restrict__ W, const float* __restrict__ Wpos,
    const float* __restrict__ bpos, float* __restrict__ outIdx)
{
  __shared__ float4 sca[LSEQ];             // xyz + mask in .w (16 KB)
  __shared__ unsigned qhi[4][64][17];
  __shared__ unsigned qlo[4][64][17];
  int blk = blockIdx.x, tid = threadIdx.x;

  if (blk >= 1024) {                       // ---- prep blocks
    int pb = blk - 1024;
    if (pb < 16) {                         // atoms + Cb
      int t = pb*256 + tid;
      const float* p = X + (size_t)t*12;
      float nx=p[0],ny=p[1],nz=p[2];
      float cax=p[3],cay=p[4],caz=p[5];
      float cx=p[6],cy=p[7],cz=p[8];
      float ox=p[9],oy=p[10],oz=p[11];
      float bx=cax-nx, by=cay-ny, bz=caz-nz;
      float ex=cx-cax, ey=cy-cay, ez=cz-caz;
      float ax2 = by*ez - bz*ey;
      float ay2 = bz*ex - bx*ez;
      float az2 = bx*ey - by*ex;
      float cbx = -0.58273431f*ax2 + 0.56802827f*bx - 0.54067466f*ex + cax;
      float cby = -0.58273431f*ay2 + 0.56802827f*by - 0.54067466f*ey + cay;
      float cbz = -0.58273431f*az2 + 0.56802827f*bz - 0.54067466f*ez + caz;
      g_atoms[t*5+0] = make_float4(nx,ny,nz,0.f);
      g_atoms[t*5+1] = make_float4(cax,cay,caz,0.f);
      g_atoms[t*5+2] = make_float4(cx,cy,cz,0.f);
      g_atoms[t*5+3] = make_float4(ox,oy,oz,0.f);
      g_atoms[t*5+4] = make_float4(cbx,cby,cbz,0.f);
    } else if (pb < 32) {                  // W_edge -> bf16 (16 blocks x 13 iters)
      int base = (pb-16)*3328 + tid;
      #pragma unroll
      for (int q = 0; q < 13; ++q) g_wbf[base + q*256] = f2bf(W[base + q*256]);
    } else {                               // WposT table
      for (int t = tid; t < 66*16; t += 256) {
        int d = t >> 4, c = t & 15;
        g_wpt[t] = f2bf(Wpos[c*66 + d] + bpos[c]);
      }
    }
    return;
  }

  // ---- top-K block
  int b = blk >> 8, chunk = blk & 255;
  for (int t = tid; t < LSEQ; t += 256) {
    const float* p = X + (size_t)(b*LSEQ + t)*12 + 3;   // Ca
    sca[t] = make_float4(p[0], p[1], p[2], mask[b*LSEQ + t]);
  }
  __syncthreads();
  int wv = tid >> 6, lane = tid & 63;
  int i = chunk*4 + wv;
  float4 ci = sca[i];
  float  mi = ci.w;

  float Dv[16]; float dmax = 0.f;
  #pragma unroll
  for (int q = 0; q < 16; ++q) {
    int j = lane + (q << 6);
    float4 cj = sca[j];
    // bit-exact vs XLA: separate mul/add (no FMA), correctly-rounded sqrt
    float dx = __fsub_rn(cj.x, ci.x);
    float dy = __fsub_rn(cj.y, ci.y);
    float dz = __fsub_rn(cj.z, ci.z);
    float s  = __fadd_rn(__fadd_rn(__fmul_rn(dx,dx), __fmul_rn(dy,dy)), __fmul_rn(dz,dz));
    float sq = __fsqrt_rn(__fadd_rn(s, 1e-6f));
    float d  = __fmul_rn(__fmul_rn(mi, cj.w), sq);
    Dv[q] = d;
    dmax = fmaxf(dmax, d);
  }
  #pragma unroll
  for (int o = 32; o; o >>= 1) dmax = fmaxf(dmax, __shfl_xor(dmax, o, 64));

  unsigned long long key[16];
  #pragma unroll
  for (int q = 0; q < 16; ++q) {
    int j = lane + (q << 6);
    float m2   = __fmul_rn(mi, sca[j].w);
    float dadj = __fadd_rn(Dv[q], __fmul_rn(__fsub_rn(1.0f, m2), dmax));
    key[q] = ((unsigned long long)__float_as_uint(dadj) << 32) | (unsigned)j;
  }

  // Batcher odd-even mergesort of the 16 per-lane keys (ascending)
  #pragma unroll
  for (int p = 1; p < 16; p <<= 1)
    #pragma unroll
    for (int k = p; k >= 1; k >>= 1)
      #pragma unroll
      for (int j = k & (p - 1); j + k < 16; j += 2*k)
        #pragma unroll
        for (int u = 0; u < k; ++u)
          if (u + j + k < 16 && ((u + j) / (2*p) == (u + j + k) / (2*p))) {
            unsigned long long a = key[u+j], c2 = key[u+j+k];
            if (a > c2) { key[u+j] = c2; key[u+j+k] = a; }
          }

  #pragma unroll
  for (int q = 0; q < 16; ++q) {
    qhi[wv][lane][q] = (unsigned)(key[q] >> 32);
    qlo[wv][lane][q] = (unsigned)key[q];
  }
  // no barrier: each lane re-reads only its own queue

  unsigned hhi = (unsigned)(key[0] >> 32), hlo = (unsigned)key[0];
  int pos = 0;
  size_t row = (size_t)(b*LSEQ + i);
  for (int k = 0; k < KNB; ++k) {
    unsigned mh = wave_umin(hhi);
    unsigned long long bmask = __ballot(hhi == mh);
    bool own;
    if (__popcll(bmask) == 1) {
      own = (hhi == mh);
    } else {                              // hi tie: min index wins
      unsigned jv = (hhi == mh) ? hlo : 0xFFFFFFFFu;
      unsigned mj = wave_umin(jv);
      own = (hhi == mh) && (hlo == mj);
    }
    if (own) {
      g_nbr[row*KNB + k] = (int)hlo;
      g_dnb[row*KNB + k] = __uint_as_float(mh);
      outIdx[row*KNB + k] = (float)(int)hlo;
      ++pos;
      if (pos < 16) { hhi = qhi[wv][lane][pos]; hlo = qlo[wv][lane][pos]; }
      else          { hhi = 0xFFFFFFFFu; hlo = 0xFFFFFFFFu; }
    }
  }
}

// ---------------- kernel 2: features (chain-RBF, swizzled LDS) + pipelined MFMA + fused LN ----------------
// LDS overlay: sstat/rstat live in the atN region (atN dead after feat pass 1's barrier,
// sstat first written after GEMM pass 1) -> 28.9 KB total -> 5 blocks/CU.
__global__ __launch_bounds__(256, 5) void k_edge(
    const int* __restrict__ ridx, const int* __restrict__ chain,
    const float* __restrict__ lng, const float* __restrict__ lnb,
    float* __restrict__ out)
{
  __shared__ __align__(16) ushort featb[KNB*256];   // 24,576 B; 32B slots, slot^(k&7) swizzle
  __shared__ __align__(16) unsigned char atn_mem[KNB*5*16];  // 3,840 B, time-multiplexed
  float4* atN   = (float4*)atn_mem;                 // [KNB*5], phases A..feat1
  float2* sstat = (float2*)atn_mem;                 // [KNB][4], epilogue
  float2* rstat = (float2*)(atn_mem + 1536);        // [KNB],   epilogue
  __shared__ float4 atI[5];
  __shared__ float  sdn[KNB];
  __shared__ int    sdd[KNB];

  int node = blockIdx.x;               // b*LSEQ + i
  int b = node >> 10;
  size_t ebase = (size_t)node * KNB;
  int t = threadIdx.x;

  // ---- phase A: scalars + atom gather
  if (t < KNB) {
    int j = g_nbr[ebase + t];
    sdn[t] = g_dnb[ebase + t];
    int off = ridx[node] - ridx[b*LSEQ + j];
    bool same = (chain[node] == chain[b*LSEQ + j]);
    int dcl = min(max(off + 32, 0), 64);
    sdd[t] = same ? dcl : 65;
  }
  if (t >= 64 && t < 69) atI[t-64] = g_atoms[node*5 + (t-64)];
  for (int u = t; u < KNB*5; u += 256) {
    int k = u / 5, a = u % 5;
    atN[u] = g_atoms[(b*LSEQ + g_nbr[ebase + k])*5 + a];
  }
  __syncthreads();

  // ---- chain-RBF writer: centers equispaced by DLT in u-units, so the
  //      Gaussian ratio e[m+1]/e[m] is geometric (x INVK per step).
  //      Two 8-element chains from both ends avoid underflow at the peak.
  auto rbf_store = [&](int k, int slot, float d) {
    const float TDLT = 2.56239448f;     // 2*DLT
    const float NDSQ = -1.64146638f;    // -DLT^2
    const float INVK = 0.10274013f;     // exp2(-2*DLT^2)
    float u0  = __fmaf_rn(d, 0.96089793f, -1.92179585f);
    float u15 = u0 - 19.21795854f;      // u at center 15
    float e[16];
    float eA = __builtin_amdgcn_exp2f(-(u0*u0));
    float rA = __builtin_amdgcn_exp2f(__fmaf_rn(u0, TDLT, NDSQ));
    float eB = __builtin_amdgcn_exp2f(-(u15*u15));
    float rB = __builtin_amdgcn_exp2f(__fmaf_rn(u15, -TDLT, NDSQ));
    e[0] = eA; e[15] = eB;
    #pragma unroll
    for (int j2 = 1; j2 < 8; ++j2) {
      eA *= rA; rA *= INVK; e[j2] = eA;        // ascending from m=0
      eB *= rB; rB *= INVK; e[15-j2] = eB;     // descending from m=15
    }
    union { s16x8 v; unsigned w[4]; } a0, a1;
    #pragma unroll
    for (int q = 0; q < 4; ++q) {
      a0.w[q] = pack2bf(e[2*q],   e[2*q+1]);
      a1.w[q] = pack2bf(e[8+2*q], e[8+2*q+1]);
    }
    ushort* fp = &featb[k*256 + ((slot ^ (k & 7)) << 4)];
    *(s16x8*)fp       = a0.v;
    *(s16x8*)(fp + 8) = a1.v;
  };

  // ---- feat pass 0: E_pos (slot 0) + RBF p=0..12 (slots 1..13)
  if (t < 96) {
    int k = t >> 1, h = t & 1;
    *(s16x8*)&featb[k*256 + ((0 ^ (k & 7)) << 4) + h*8] =
        *(const s16x8*)&g_wpt[sdd[k]*16 + h*8];
  }
  for (int u = t; u < KNB*13; u += 256) {
    int k = u / 13, p = u % 13;
    float d;
    if (p == 0) d = sdn[k];
    else {
      float4 A = atI[cPA[p-1]];
      float4 Bv = atN[k*5 + cPB[p-1]];
      float dx = A.x-Bv.x, dy = A.y-Bv.y, dz = A.z-Bv.z;
      d = sqrtf(dx*dx + dy*dy + dz*dz + 1e-6f);
    }
    rbf_store(k, p + 1, d);
  }
  __syncthreads();

  int ln = t & 63, wv = t >> 6;
  int fr = ln & 15, fq = ln >> 4;
  int n0 = wv * 32;
  f32x4 acc[3][2];
  #pragma unroll
  for (int mt = 0; mt < 3; ++mt) { acc[mt][0] = (f32x4)0.f; acc[mt][1] = (f32x4)0.f; }
  const ushort* w0 = &g_wbf[(n0 + fr)*NFEAT];
  const ushort* w1 = &g_wbf[(n0 + 16 + fr)*NFEAT];

  // 2-stage-pipelined GEMM pass: featb local k from 0, W offset WOFF
#define GEMM_PASS(WOFF, NSTEPS)                                                     \
  {                                                                                 \
    s16x8 cw0 = *(const s16x8*)&w0[(WOFF) + fq*8];                                  \
    s16x8 cw1 = *(const s16x8*)&w1[(WOFF) + fq*8];                                  \
    _Pragma("unroll")                                                               \
    for (int s = 0; s < (NSTEPS); ++s) {                                            \
      int kk = s*32 + fq*8;                                                         \
      s16x8 nw0, nw1;                                                               \
      if (s + 1 < (NSTEPS)) {                                                       \
        nw0 = *(const s16x8*)&w0[(WOFF) + kk + 32];                                 \
        nw1 = *(const s16x8*)&w1[(WOFF) + kk + 32];                                 \
      }                                                                             \
      _Pragma("unroll")                                                             \
      for (int mt = 0; mt < 3; ++mt) {                                              \
        int row = mt*16 + fr;                                                       \
        s16x8 af = *(const s16x8*)&featb[row*256 + (((kk >> 4) ^ (fr & 7)) << 4) + (kk & 8)]; \
        acc[mt][0] = __builtin_amdgcn_mfma_f32_16x16x32_bf16(af, cw0, acc[mt][0], 0, 0, 0);   \
        acc[mt][1] = __builtin_amdgcn_mfma_f32_16x16x32_bf16(af, cw1, acc[mt][1], 0, 0, 0);   \
      }                                                                             \
      if (s + 1 < (NSTEPS)) { cw0 = nw0; cw1 = nw1; }                               \
    }                                                                               \
  }

  // ---- GEMM pass 0: features [0,224), 7 K-steps
  GEMM_PASS(0, 7)
  __syncthreads();   // pass-0 reads done before overwrite

  // ---- feat pass 1: RBF p=13..24 (slots 0..11) -- last atN reads
  for (int u = t; u < KNB*12; u += 256) {
    int k = u / 12, p = 13 + u % 12;
    float4 A = atI[cPA[p-1]];
    float4 Bv = atN[k*5 + cPB[p-1]];
    float dx = A.x-Bv.x, dy = A.y-Bv.y, dz = A.z-Bv.z;
    rbf_store(k, p - 13, sqrtf(dx*dx + dy*dy + dz*dz + 1e-6f));
  }
  __syncthreads();   // after this barrier atN is dead -> sstat/rstat may overwrite

  // ---- GEMM pass 1: features [224,416), 6 K-steps
  GEMM_PASS(224, 6)

  // ---- fused LayerNorm epilogue; row sums via DPP row_ror (VALU-only)
  #pragma unroll
  for (int mt = 0; mt < 3; ++mt)
    #pragma unroll
    for (int i2 = 0; i2 < 4; ++i2) {
      float v0 = acc[mt][0][i2], v1 = acc[mt][1][i2];
      float s = v0 + v1, sq = v0*v0 + v1*v1;
      DPP_ADD_F(s, 0x128) DPP_ADD_F(s, 0x124) DPP_ADD_F(s, 0x122) DPP_ADD_F(s, 0x121)
      DPP_ADD_F(sq, 0x128) DPP_ADD_F(sq, 0x124) DPP_ADD_F(sq, 0x122) DPP_ADD_F(sq, 0x121)
      if (fr == 0) sstat[(mt*16 + fq*4 + i2)*4 + wv] = make_float2(s, sq);
    }
  __syncthreads();
  if (t < KNB) {
    float s = 0.f, sq = 0.f;
    #pragma unroll
    for (int w = 0; w < 4; ++w) { float2 pp = sstat[t*4 + w]; s += pp.x; sq += pp.y; }
    float mu  = s * (1.0f/128.0f);
    float var = sq * (1.0f/128.0f) - mu*mu;
    rstat[t] = make_float2(mu, rsqrtf(var + 1e-5f));
  }
  __syncthreads();
  float gn0 = lng[n0+fr], gn1 = lng[n0+16+fr];
  float bn0 = lnb[n0+fr], bn1 = lnb[n0+16+fr];
  #pragma unroll
  for (int mt = 0; mt < 3; ++mt)
    #pragma unroll
    for (int i2 = 0; i2 < 4; ++i2) {
      int row = mt*16 + fq*4 + i2;
      float2 mr = rstat[row];
      size_t ob = (ebase + row) * NOUT;
      out[ob + n0 + fr]      = (acc[mt][0][i2] - mr.x) * mr.y * gn0 + bn0;
      out[ob + n0 + 16 + fr] = (acc[mt][1][i2] - mr.x) * mr.y * gn1 + bn1;
    }
}

extern "C" void kernel_launch(void* const* d_in, const int* in_sizes, int n_in,
                              void* d_out, int out_size, void* d_ws, size_t ws_size,
                              hipStream_t stream) {
  const float* X     = (const float*)d_in[0];
  const float* mask  = (const float*)d_in[1];
  const int*   ridx  = (const int*)d_in[2];
  const int*   chain = (const int*)d_in[3];
  const float* Wpos  = (const float*)d_in[4];
  const float* bpos  = (const float*)d_in[5];
  const float* Wedge = (const float*)d_in[6];
  const float* lng   = (const float*)d_in[7];
  const float* lnb   = (const float*)d_in[8];
  float* out = (float*)d_out;
  float* outIdx = out + (size_t)NNODE*KNB*NOUT;

  k_front<<<dim3(1024 + 33), dim3(256), 0, stream>>>(X, mask, Wedge, Wpos, bpos, outIdx);
  k_edge<<<dim3(NNODE), dim3(256), 0, stream>>>(ridx, chain, lng, lnb, out);
}

// Round 15
// 76.657 us; speedup vs baseline: 1.5416x; 1.0585x over previous
//
#include <hip/hip_runtime.h>
#include <stdint.h>

#define LSEQ 1024
#define NB 4
#define KNB 48
#define NFEAT 416   // 16 + 25*16
#define NOUT 128
#define NNODE (NB*LSEQ)

typedef float f32x4 __attribute__((ext_vector_type(4)));
typedef short s16x8 __attribute__((ext_vector_type(8)));

// static device scratch -- fully rewritten every call before use
__device__ float4 g_atoms[NNODE*5];
__device__ ushort g_wbf[NOUT*NFEAT];   // W_edge bf16, row-major [e][f]
__device__ ushort g_wpt[66*16];        // (W_pos.T + b_pos) bf16, [d][c]

__constant__ int cPA[24] = {0,2,3,4,1,1,1,1,0,0,0,4,4,3,0,2,3,4,2,3,4,2,3,2};
__constant__ int cPB[24] = {0,2,3,4,0,2,3,4,2,3,4,2,3,2,1,1,1,1,0,0,0,4,4,3};

__device__ __forceinline__ ushort f2bf(float x) {      // RNE (weights)
  unsigned u = __float_as_uint(x);
  u += 0x7fffu + ((u >> 16) & 1u);
  return (ushort)(u >> 16);
}
// pack trunc-bf16(lo), trunc-bf16(hi) into one dword via byte-perm
__device__ __forceinline__ unsigned pack2bf(float lo, float hi) {
  return __builtin_amdgcn_perm(__float_as_uint(hi), __float_as_uint(lo), 0x07060302u);
}

#define DPP_ADD_F(x, CTRL) { int _y = __builtin_amdgcn_mov_dpp(__float_as_int(x), CTRL, 0xF, 0xF, true); x += __int_as_float(_y); }
#define DPP_MIN_U(x, CTRL) { unsigned _y = (unsigned)__builtin_amdgcn_mov_dpp((int)(x), CTRL, 0xF, 0xF, true); x = min(x, _y); }

__device__ __forceinline__ unsigned wave_umin(unsigned x) {
  DPP_MIN_U(x, 0x128) DPP_MIN_U(x, 0x124) DPP_MIN_U(x, 0x122) DPP_MIN_U(x, 0x121)
  x = min(x, (unsigned)__shfl_xor((int)x, 16, 64));
  x = min(x, (unsigned)__shfl_xor((int)x, 32, 64));
  return x;
}

// ---------------- kernel 0: atoms/Cb + W->bf16 + WposT table ----------------
__global__ void k_pre(const float* __restrict__ X, const float* __restrict__ W,
                      const float* __restrict__ Wpos, const float* __restrict__ bpos) {
  int blk = blockIdx.x, tid = threadIdx.x;
  if (blk < 16) {                          // atoms + Cb
    int t = blk*256 + tid;
    const float* p = X + (size_t)t*12;
    float nx=p[0],ny=p[1],nz=p[2];
    float cax=p[3],cay=p[4],caz=p[5];
    float cx=p[6],cy=p[7],cz=p[8];
    float ox=p[9],oy=p[10],oz=p[11];
    float bx=cax-nx, by=cay-ny, bz=caz-nz;
    float ex=cx-cax, ey=cy-cay, ez=cz-caz;
    float ax2 = by*ez - bz*ey;
    float ay2 = bz*ex - bx*ez;
    float az2 = bx*ey - by*ex;
    float cbx = -0.58273431f*ax2 + 0.56802827f*bx - 0.54067466f*ex + cax;
    float cby = -0.58273431f*ay2 + 0.56802827f*by - 0.54067466f*ey + cay;
    float cbz = -0.58273431f*az2 + 0.56802827f*bz - 0.54067466f*ez + caz;
    g_atoms[t*5+0] = make_float4(nx,ny,nz,0.f);
    g_atoms[t*5+1] = make_float4(cax,cay,caz,0.f);
    g_atoms[t*5+2] = make_float4(cx,cy,cz,0.f);
    g_atoms[t*5+3] = make_float4(ox,oy,oz,0.f);
    g_atoms[t*5+4] = make_float4(cbx,cby,cbz,0.f);
  } else if (blk < 32) {                   // W_edge -> bf16 (16 blocks x 13 iters)
    int base = (blk-16)*3328 + tid;
    #pragma unroll
    for (int q = 0; q < 13; ++q) g_wbf[base + q*256] = f2bf(W[base + q*256]);
  } else {                                 // WposT table
    for (int t = tid; t < 66*16; t += 256) {
      int d = t >> 4, c = t & 15;
      g_wpt[t] = f2bf(Wpos[c*66 + d] + bpos[c]);
    }
  }
}

// ---------------- kernel 1: FUSED 4-node block: parallel top-K + edge pipeline ----------------
// LDS union U (32 KB), time-multiplexed:
//   P0/P1: sca[1024] float4 (16 KB)           -- staging + key-gen
//   P2:    qhi/qlo [4][16][64] u32 (32 KB)    -- sorted queues + extraction
//   P3+:   featb 24,576 B + atN 3,840 B       -- edge pipeline (sstat/rstat overlay atN)
__global__ __launch_bounds__(256, 4) void k_main(
    const float* __restrict__ X, const float* __restrict__ mask,
    const int* __restrict__ ridx, const int* __restrict__ chain,
    const float* __restrict__ lng, const float* __restrict__ lnb,
    float* __restrict__ out, float* __restrict__ outIdx)
{
  __shared__ __align__(16) unsigned char U[32768];
  float4*   sca   = (float4*)U;                       // [1024]
  unsigned* qhi   = (unsigned*)U;                     // [(wv*16+pos)*64 + lane]
  unsigned* qlo   = (unsigned*)(U + 16384);
  ushort*   featb = (ushort*)U;                       // [48*256]
  float4*   atN   = (float4*)(U + 24576);             // [240]
  float2*   sstat = (float2*)(U + 24576);             // [48][4] (overlay atN, epilogue)
  float2*   rstat = (float2*)(U + 24576 + 1536);      // [48]
  __shared__ float4 atI[5];
  __shared__ int   snbrA[4][KNB];
  __shared__ float sdnA[4][KNB];
  __shared__ int   sddA[4][KNB];

  int t = threadIdx.x, ln = t & 63, wv = t >> 6;
  int blk = blockIdx.x;
  int b = blk >> 8, chunk = blk & 255;
  int node0 = b*LSEQ + chunk*4;

  // ---- P0: stage Ca + mask
  for (int u = t; u < LSEQ; u += 256) {
    const float* p = X + (size_t)(b*LSEQ + u)*12 + 3;   // Ca
    sca[u] = make_float4(p[0], p[1], p[2], mask[b*LSEQ + u]);
  }
  __syncthreads();

  // ---- P1: per-wave key generation for row (chunk*4 + wv); bit-exact vs XLA
  int irow = chunk*4 + wv;
  float4 ci = sca[irow];
  float  mi = ci.w;
  float Dv[16]; float dmax = 0.f;
  #pragma unroll
  for (int q = 0; q < 16; ++q) {
    int j = ln + (q << 6);
    float4 cj = sca[j];
    float dx = __fsub_rn(cj.x, ci.x);
    float dy = __fsub_rn(cj.y, ci.y);
    float dz = __fsub_rn(cj.z, ci.z);
    float s  = __fadd_rn(__fadd_rn(__fmul_rn(dx,dx), __fmul_rn(dy,dy)), __fmul_rn(dz,dz));
    float sq = __fsqrt_rn(__fadd_rn(s, 1e-6f));
    float d  = __fmul_rn(__fmul_rn(mi, cj.w), sq);
    Dv[q] = d;
    dmax = fmaxf(dmax, d);
  }
  #pragma unroll
  for (int o = 32; o; o >>= 1) dmax = fmaxf(dmax, __shfl_xor(dmax, o, 64));

  unsigned long long key[16];
  #pragma unroll
  for (int q = 0; q < 16; ++q) {
    int j = ln + (q << 6);
    float m2   = __fmul_rn(mi, sca[j].w);
    float dadj = __fadd_rn(Dv[q], __fmul_rn(__fsub_rn(1.0f, m2), dmax));
    key[q] = ((unsigned long long)__float_as_uint(dadj) << 32) | (unsigned)j;
  }

  // Batcher odd-even mergesort of the 16 per-lane keys (ascending)
  #pragma unroll
  for (int p = 1; p < 16; p <<= 1)
    #pragma unroll
    for (int k = p; k >= 1; k >>= 1)
      #pragma unroll
      for (int j = k & (p - 1); j + k < 16; j += 2*k)
        #pragma unroll
        for (int u = 0; u < k; ++u)
          if (u + j + k < 16 && ((u + j) / (2*p) == (u + j + k) / (2*p))) {
            unsigned long long a = key[u+j], c2 = key[u+j+k];
            if (a > c2) { key[u+j] = c2; key[u+j+k] = a; }
          }
  __syncthreads();   // last sca read done (keys live in registers) -> queue region free

  // ---- P2: queues + extraction (each wave its own row)
  #pragma unroll
  for (int q = 0; q < 16; ++q) {
    qhi[(wv*16 + q)*64 + ln] = (unsigned)(key[q] >> 32);
    qlo[(wv*16 + q)*64 + ln] = (unsigned)key[q];
  }
  // no wave-internal barrier: each lane re-reads only its own queue entries
  {
    unsigned hhi = (unsigned)(key[0] >> 32), hlo = (unsigned)key[0];
    int pos = 0;
    size_t row = (size_t)(node0 + wv);
    for (int k = 0; k < KNB; ++k) {
      unsigned mh = wave_umin(hhi);
      unsigned long long bmask = __ballot(hhi == mh);
      bool own;
      if (__popcll(bmask) == 1) {
        own = (hhi == mh);
      } else {                            // hi tie: min index wins
        unsigned jv = (hhi == mh) ? hlo : 0xFFFFFFFFu;
        unsigned mj = wave_umin(jv);
        own = (hhi == mh) && (hlo == mj);
      }
      if (own) {
        snbrA[wv][k] = (int)hlo;
        sdnA[wv][k]  = __uint_as_float(mh);
        outIdx[row*KNB + k] = (float)(int)hlo;
        ++pos;
        if (pos < 16) { hhi = qhi[(wv*16 + pos)*64 + ln]; hlo = qlo[(wv*16 + pos)*64 + ln]; }
        else          { hhi = 0xFFFFFFFFu; hlo = 0xFFFFFFFFu; }
      }
    }
  }
  __syncthreads();   // queues dead; snbrA/sdnA valid for all waves

  // ---- positional buckets for all 4 nodes at once
  if (t < 192) {
    int it = t / KNB, k = t % KNB;
    int nd = node0 + it;
    int j = snbrA[it][k];
    int off = ridx[nd] - ridx[b*LSEQ + j];
    bool same = (chain[nd] == chain[b*LSEQ + j]);
    sddA[it][k] = same ? min(max(off + 32, 0), 64) : 65;
  }

  // ---- chain-RBF writer (r11 proven)
  auto rbf_store = [&](int k, int slot, float d) {
    const float TDLT = 2.56239448f;     // 2*DLT
    const float NDSQ = -1.64146638f;    // -DLT^2
    const float INVK = 0.10274013f;     // exp2(-2*DLT^2)
    float u0  = __fmaf_rn(d, 0.96089793f, -1.92179585f);
    float u15 = u0 - 19.21795854f;
    float e[16];
    float eA = __builtin_amdgcn_exp2f(-(u0*u0));
    float rA = __builtin_amdgcn_exp2f(__fmaf_rn(u0, TDLT, NDSQ));
    float eB = __builtin_amdgcn_exp2f(-(u15*u15));
    float rB = __builtin_amdgcn_exp2f(__fmaf_rn(u15, -TDLT, NDSQ));
    e[0] = eA; e[15] = eB;
    #pragma unroll
    for (int j2 = 1; j2 < 8; ++j2) {
      eA *= rA; rA *= INVK; e[j2] = eA;
      eB *= rB; rB *= INVK; e[15-j2] = eB;
    }
    union { s16x8 v; unsigned w[4]; } a0, a1;
    #pragma unroll
    for (int q = 0; q < 4; ++q) {
      a0.w[q] = pack2bf(e[2*q],   e[2*q+1]);
      a1.w[q] = pack2bf(e[8+2*q], e[8+2*q+1]);
    }
    ushort* fp = &featb[k*256 + ((slot ^ (k & 7)) << 4)];
    *(s16x8*)fp       = a0.v;
    *(s16x8*)(fp + 8) = a1.v;
  };

  int fr = ln & 15, fq = ln >> 4;
  int n0 = wv * 32;
  const ushort* w0 = &g_wbf[(n0 + fr)*NFEAT];
  const ushort* w1 = &g_wbf[(n0 + 16 + fr)*NFEAT];
  float gn0 = lng[n0+fr], gn1 = lng[n0+16+fr];
  float bn0 = lnb[n0+fr], bn1 = lnb[n0+16+fr];

#define GEMM_PASS(WOFF, NSTEPS)                                                     \
  {                                                                                 \
    s16x8 cw0 = *(const s16x8*)&w0[(WOFF) + fq*8];                                  \
    s16x8 cw1 = *(const s16x8*)&w1[(WOFF) + fq*8];                                  \
    _Pragma("unroll")                                                               \
    for (int s = 0; s < (NSTEPS); ++s) {                                            \
      int kk = s*32 + fq*8;                                                         \
      s16x8 nw0, nw1;                                                               \
      if (s + 1 < (NSTEPS)) {                                                       \
        nw0 = *(const s16x8*)&w0[(WOFF) + kk + 32];                                 \
        nw1 = *(const s16x8*)&w1[(WOFF) + kk + 32];                                 \
      }                                                                             \
      _Pragma("unroll")                                                             \
      for (int mt = 0; mt < 3; ++mt) {                                              \
        int row = mt*16 + fr;                                                       \
        s16x8 af = *(const s16x8*)&featb[row*256 + (((kk >> 4) ^ (fr & 7)) << 4) + (kk & 8)]; \
        acc[mt][0] = __builtin_amdgcn_mfma_f32_16x16x32_bf16(af, cw0, acc[mt][0], 0, 0, 0);   \
        acc[mt][1] = __builtin_amdgcn_mfma_f32_16x16x32_bf16(af, cw1, acc[mt][1], 0, 0, 0);   \
      }                                                                             \
      if (s + 1 < (NSTEPS)) { cw0 = nw0; cw1 = nw1; }                               \
    }                                                                               \
  }

  // ---- edge pipeline, 4 nodes sequentially
  #pragma unroll 1
  for (int it = 0; it < 4; ++it) {
    int node = node0 + it;
    size_t ebase = (size_t)node * KNB;

    // phase A: atI + atN gather
    if (t < 5) atI[t] = g_atoms[node*5 + t];
    for (int u = t; u < KNB*5; u += 256) {
      int k = u / 5, a = u % 5;
      atN[u] = g_atoms[(b*LSEQ + snbrA[it][k])*5 + a];
    }
    __syncthreads();

    // feat pass 0: E_pos (slot 0) + RBF p=0..12 (slots 1..13)
    if (t < 96) {
      int k = t >> 1, h = t & 1;
      *(s16x8*)&featb[k*256 + ((0 ^ (k & 7)) << 4) + h*8] =
          *(const s16x8*)&g_wpt[sddA[it][k]*16 + h*8];
    }
    for (int u = t; u < KNB*13; u += 256) {
      int k = u / 13, p = u % 13;
      float d;
      if (p == 0) d = sdnA[it][k];
      else {
        float4 A = atI[cPA[p-1]];
        float4 Bv = atN[k*5 + cPB[p-1]];
        float dx = A.x-Bv.x, dy = A.y-Bv.y, dz = A.z-Bv.z;
        d = sqrtf(dx*dx + dy*dy + dz*dz + 1e-6f);
      }
      rbf_store(k, p + 1, d);
    }
    __syncthreads();

    f32x4 acc[3][2];
    #pragma unroll
    for (int mt = 0; mt < 3; ++mt) { acc[mt][0] = (f32x4)0.f; acc[mt][1] = (f32x4)0.f; }

    GEMM_PASS(0, 7)
    __syncthreads();   // pass-0 featb reads done before overwrite

    // feat pass 1: RBF p=13..24 (slots 0..11) -- last atN reads
    for (int u = t; u < KNB*12; u += 256) {
      int k = u / 12, p = 13 + u % 12;
      float4 A = atI[cPA[p-1]];
      float4 Bv = atN[k*5 + cPB[p-1]];
      float dx = A.x-Bv.x, dy = A.y-Bv.y, dz = A.z-Bv.z;
      rbf_store(k, p - 13, sqrtf(dx*dx + dy*dy + dz*dz + 1e-6f));
    }
    __syncthreads();   // atN dead -> sstat/rstat may overwrite

    GEMM_PASS(224, 6)

    // fused LayerNorm epilogue
    #pragma unroll
    for (int mt = 0; mt < 3; ++mt)
      #pragma unroll
      for (int i2 = 0; i2 < 4; ++i2) {
        float v0 = acc[mt][0][i2], v1 = acc[mt][1][i2];
        float s = v0 + v1, sq = v0*v0 + v1*v1;
        DPP_ADD_F(s, 0x128) DPP_ADD_F(s, 0x124) DPP_ADD_F(s, 0x122) DPP_ADD_F(s, 0x121)
        DPP_ADD_F(sq, 0x128) DPP_ADD_F(sq, 0x124) DPP_ADD_F(sq, 0x122) DPP_ADD_F(sq, 0x121)
        if (fr == 0) sstat[(mt*16 + fq*4 + i2)*4 + wv] = make_float2(s, sq);
      }
    __syncthreads();
    if (t < KNB) {
      float s = 0.f, sq = 0.f;
      #pragma unroll
      for (int w = 0; w < 4; ++w) { float2 pp = sstat[t*4 + w]; s += pp.x; sq += pp.y; }
      float mu  = s * (1.0f/128.0f);
      float var = sq * (1.0f/128.0f) - mu*mu;
      rstat[t] = make_float2(mu, rsqrtf(var + 1e-5f));
    }
    __syncthreads();
    #pragma unroll
    for (int mt = 0; mt < 3; ++mt)
      #pragma unroll
      for (int i2 = 0; i2 < 4; ++i2) {
        int row = mt*16 + fq*4 + i2;
        float2 mr = rstat[row];
        size_t ob = (ebase + row) * NOUT;
        out[ob + n0 + fr]      = (acc[mt][0][i2] - mr.x) * mr.y * gn0 + bn0;
        out[ob + n0 + 16 + fr] = (acc[mt][1][i2] - mr.x) * mr.y * gn1 + bn1;
      }
    __syncthreads();   // rstat reads done before next iteration's atN write
  }
}

extern "C" void kernel_launch(void* const* d_in, const int* in_sizes, int n_in,
                              void* d_out, int out_size, void* d_ws, size_t ws_size,
                              hipStream_t stream) {
  const float* X     = (const float*)d_in[0];
  const float* mask  = (const float*)d_in[1];
  const int*   ridx  = (const int*)d_in[2];
  const int*   chain = (const int*)d_in[3];
  const float* Wpos  = (const float*)d_in[4];
  const float* bpos  = (const float*)d_in[5];
  const float* Wedge = (const float*)d_in[6];
  const float* lng   = (const float*)d_in[7];
  const float* lnb   = (const float*)d_in[8];
  float* out = (float*)d_out;
  float* outIdx = out + (size_t)NNODE*KNB*NOUT;

  k_pre<<<dim3(33), dim3(256), 0, stream>>>(X, Wedge, Wpos, bpos);
  k_main<<<dim3(1024), dim3(256), 0, stream>>>(X, mask, ridx, chain, lng, lnb, out, outIdx);
}